// Round 1
// baseline (31281.912 us; speedup 1.0000x reference)
//
#include <hip/hip_runtime.h>
#include <hip/hip_bf16.h>
#include <hip/hip_cooperative_groups.h>
#include <cstdint>
#include <cstddef>

namespace cg = cooperative_groups;

#define H   1024
#define D   80
#define DP  96          // D padded to multiple of 32 (zero-padded)
#define T   512
#define B   64
#define NG  32          // gate rows per block (4 gates x 8 hidden units)
#define KP  1032        // LDS row stride for Whh slice (+8 bf16 pad -> kills 16-way bank conflict)
#define KPI 104         // LDS row stride for Wih slice

typedef __attribute__((ext_vector_type(8))) short bf16x8;   // 8 bf16 in 4 VGPRs (MFMA A/B frag)
typedef __attribute__((ext_vector_type(4))) float f32x4;    // MFMA C/D frag

// ws layout
#define HBUF_ELEMS ((size_t)2 * (T + 1) * B * H)            // bf16 h history, slot 0 = h_{-1}=0
#define HBUF_BYTES (HBUF_ELEMS * 2)
#define XS_ELEMS   ((size_t)T * B * DP)                     // bf16 teacher-forced inputs (padded)
#define XS_BYTES   (XS_ELEMS * 2)
#define WOUT_ELEMS ((size_t)2 * D * H)                      // bf16 W_out for both decoders
#define WOUT_BYTES (WOUT_ELEMS * 2)

__device__ __forceinline__ unsigned short f2bf(float x) {
    unsigned int u = __float_as_uint(x);
    unsigned int r = (u + 0x7FFFu + ((u >> 16) & 1u)) >> 16;   // RNE
    return (unsigned short)r;
}

// ---- prep: x0 = input[T-1] @ W_in^T + b_in  (one wave per output element) ----
__global__ void prep_x0(const float* __restrict__ inp, const float* __restrict__ Win,
                        const float* __restrict__ bin, unsigned short* __restrict__ xs)
{
    int o = blockIdx.x;                // 0 .. B*D-1
    int b = o / D, d = o % D;
    int lane = threadIdx.x;
    const float* irow = inp + ((size_t)(T - 1) * B + b) * H;
    const float* wrow = Win + (size_t)d * H;
    float s = 0.f;
    for (int k = lane; k < H; k += 64) s += irow[k] * wrow[k];
    for (int off = 32; off > 0; off >>= 1) s += __shfl_down(s, off, 64);
    if (lane == 0) xs[b * DP + d] = f2bf(s + bin[d]);
}

// ---- prep: xs[t] = target[t-1] (t>=1), zero pads everywhere ----
__global__ void prep_xs(const float* __restrict__ tgt, unsigned short* __restrict__ xs)
{
    int idx = blockIdx.x * 256 + threadIdx.x;
    if (idx >= T * B * DP) return;
    int t = idx / (B * DP);
    int r = idx % (B * DP);
    int b = r / DP, d = r % DP;
    if (d >= D) { xs[idx] = 0; return; }
    if (t == 0) return;                       // prep_x0 fills these
    xs[idx] = f2bf(tgt[((size_t)(t - 1) * B + b) * D + d]);
}

// ---- prep: convert W_out to bf16, zero h slot 0 ----
__global__ void prep_misc(const float* __restrict__ fWout, const float* __restrict__ bWout,
                          unsigned short* __restrict__ woutbf, unsigned short* __restrict__ hbuf)
{
    int idx = blockIdx.x * 256 + threadIdx.x;
    const int NW = 2 * D * H;
    const int NZ = 2 * B * H;
    if (idx < NW) {
        int dec = idx / (D * H); int rr = idx % (D * H);
        woutbf[idx] = f2bf((dec ? bWout : fWout)[rr]);
    } else if (idx < NW + NZ) {
        int z = idx - NW;
        int dec = z / (B * H); int rr = z % (B * H);
        hbuf[(size_t)dec * (T + 1) * B * H + rr] = 0;
    }
}

// ---- main persistent cooperative kernel: 256 blocks x 256 threads (1 block/CU) ----
__global__ void __launch_bounds__(256, 1)
lstm_main(unsigned short* __restrict__ hbuf,
          const unsigned short* __restrict__ xs,
          const unsigned short* __restrict__ woutbf,
          const float* __restrict__ fWih, const float* __restrict__ fWhh, const float* __restrict__ fbias,
          const float* __restrict__ bWih, const float* __restrict__ bWhh, const float* __restrict__ bbias,
          const float* __restrict__ fbout, const float* __restrict__ bbout,
          float* __restrict__ out)
{
    cg::grid_group grid = cg::this_grid();

    const int bid  = blockIdx.x;
    const int dec  = bid >> 7;          // 0 = fwd, 1 = bwd
    const int blk  = bid & 127;         // block within decoder
    const int u0   = blk << 3;          // first of 8 owned hidden units
    const int tid  = threadIdx.x;
    const int wave = tid >> 6;
    const int lane = tid & 63;
    const int l15  = lane & 15;
    const int quad = lane >> 4;
    const int koff = quad * 8;

    __shared__ unsigned short sWhh[NG][KP];    // 66 KB   W_hh slice (bf16, B-operand layout friendly)
    __shared__ unsigned short sWih[NG][KPI];   // 6.5 KB  W_ih slice (zero-padded to DP)
    __shared__ float sBias[NG];
    __shared__ float sG[B][33];                // gate dump, +1 pad
    __shared__ float sC[B][8];                 // persistent cell state slice

    const float* Wih  = dec ? bWih  : fWih;
    const float* Whh  = dec ? bWhh  : fWhh;
    const float* bias = dec ? bbias : fbias;

    // stage weights -> LDS (convert to bf16). row n of slice = gate (n>>3), unit u0+(n&7)
    for (int e = tid; e < NG * H; e += 256) {
        int n = e >> 10, k = e & (H - 1);
        int row = (n >> 3) * H + u0 + (n & 7);
        sWhh[n][k] = f2bf(Whh[(size_t)row * H + k]);
    }
    for (int e = tid; e < NG * KPI; e += 256) {
        int n = e / KPI, dd = e % KPI;
        int row = (n >> 3) * H + u0 + (n & 7);
        sWih[n][dd] = (dd < D) ? f2bf(Wih[(size_t)row * D + dd]) : 0;
    }
    if (tid < NG) {
        int row = (tid >> 3) * H + u0 + (tid & 7);
        sBias[tid] = bias[row];
    }
    for (int e = tid; e < B * 8; e += 256) sC[e >> 3][e & 7] = 0.f;
    __syncthreads();

    const int m = wave * 16 + l15;   // batch row this lane loads for A-frags

    for (int t = 0; t < T; ++t) {
        f32x4 acc0 = {0.f, 0.f, 0.f, 0.f};
        f32x4 acc1 = {0.f, 0.f, 0.f, 0.f};

        // G[64 x 32] = h_{t-1} @ Whh_slice^T   (K = 1024)
        const unsigned short* hrow = hbuf + (((size_t)(dec * (T + 1) + t) * B + m) * H);
        #pragma unroll 8
        for (int kb = 0; kb < H / 32; ++kb) {
            bf16x8 a  = *(const bf16x8*)(hrow + kb * 32 + koff);
            bf16x8 b0 = *(const bf16x8*)(&sWhh[l15][kb * 32 + koff]);
            bf16x8 b1 = *(const bf16x8*)(&sWhh[16 + l15][kb * 32 + koff]);
            acc0 = __builtin_amdgcn_mfma_f32_16x16x32_bf16(a, b0, acc0, 0, 0, 0);
            acc1 = __builtin_amdgcn_mfma_f32_16x16x32_bf16(a, b1, acc1, 0, 0, 0);
        }
        // += x_t @ Wih_slice^T   (K = 96 padded)
        const unsigned short* xrow = xs + ((size_t)t * B + m) * DP;
        #pragma unroll
        for (int kb = 0; kb < DP / 32; ++kb) {
            bf16x8 a  = *(const bf16x8*)(xrow + kb * 32 + koff);
            bf16x8 b0 = *(const bf16x8*)(&sWih[l15][kb * 32 + koff]);
            bf16x8 b1 = *(const bf16x8*)(&sWih[16 + l15][kb * 32 + koff]);
            acc0 = __builtin_amdgcn_mfma_f32_16x16x32_bf16(a, b0, acc0, 0, 0, 0);
            acc1 = __builtin_amdgcn_mfma_f32_16x16x32_bf16(a, b1, acc1, 0, 0, 0);
        }
        // C/D layout: col = lane&15, row = quad*4 + r
        #pragma unroll
        for (int r = 0; r < 4; ++r) {
            sG[wave * 16 + quad * 4 + r][l15]      = acc0[r];
            sG[wave * 16 + quad * 4 + r][16 + l15] = acc1[r];
        }
        __syncthreads();

        // elementwise: 512 (b, unit) pairs, 2 per thread
        #pragma unroll
        for (int p = tid; p < B * 8; p += 256) {
            int b = p >> 3, j = p & 7;
            float gi = sG[b][j]      + sBias[j];
            float gf = sG[b][8 + j]  + sBias[8 + j];
            float gg = sG[b][16 + j] + sBias[16 + j];
            float go = sG[b][24 + j] + sBias[24 + j];
            float i_ = 1.f / (1.f + __expf(-gi));
            float f_ = 1.f / (1.f + __expf(-gf));
            float g_ = tanhf(gg);
            float o_ = 1.f / (1.f + __expf(-go));
            float c  = f_ * sC[b][j] + i_ * g_;
            sC[b][j] = c;
            float h  = o_ * tanhf(c);
            hbuf[((size_t)(dec * (T + 1) + t + 1) * B + b) * H + u0 + j] = f2bf(h);
        }
        __threadfence();
        grid.sync();
    }

    // ---- output projection: Y[dec][t] = h_t @ W_out^T + b_out ; 4 (dec,t) tiles per block ----
    for (int qq = 0; qq < 4; ++qq) {
        int q    = bid * 4 + qq;          // 0 .. 1023
        int ydec = q >> 9;
        int yt   = q & 511;
        const float* bout = ydec ? bbout : fbout;
        const unsigned short* hr = hbuf + ((size_t)(ydec * (T + 1) + yt + 1) * B + m) * H;
        const unsigned short* wb = woutbf + (size_t)ydec * D * H;
        #pragma unroll
        for (int nt = 0; nt < 5; ++nt) {
            f32x4 acc = {0.f, 0.f, 0.f, 0.f};
            const unsigned short* wrow = wb + (size_t)(nt * 16 + l15) * H;
            #pragma unroll 8
            for (int kb = 0; kb < H / 32; ++kb) {
                bf16x8 a  = *(const bf16x8*)(hr + kb * 32 + koff);
                bf16x8 bf = *(const bf16x8*)(wrow + kb * 32 + koff);
                acc = __builtin_amdgcn_mfma_f32_16x16x32_bf16(a, bf, acc, 0, 0, 0);
            }
            float bo = bout[nt * 16 + l15];
            #pragma unroll
            for (int r = 0; r < 4; ++r) {
                int bb_ = wave * 16 + quad * 4 + r;
                out[((size_t)(ydec * T + yt) * B + bb_) * D + nt * 16 + l15] = acc[r] + bo;
            }
        }
    }
}

extern "C" void kernel_launch(void* const* d_in, const int* in_sizes, int n_in,
                              void* d_out, int out_size, void* d_ws, size_t ws_size,
                              hipStream_t stream)
{
    const float* input  = (const float*)d_in[0];
    const float* target = (const float*)d_in[1];
    const float* Win    = (const float*)d_in[2];
    const float* bin    = (const float*)d_in[3];
    const float* fWih   = (const float*)d_in[4];
    const float* fWhh   = (const float*)d_in[5];
    const float* fb     = (const float*)d_in[6];
    const float* fWout  = (const float*)d_in[7];
    const float* fbout  = (const float*)d_in[8];
    const float* bWih   = (const float*)d_in[9];
    const float* bWhh   = (const float*)d_in[10];
    const float* bb     = (const float*)d_in[11];
    const float* bWout  = (const float*)d_in[12];
    const float* bbout  = (const float*)d_in[13];
    float* out = (float*)d_out;

    unsigned short* hbuf = (unsigned short*)d_ws;
    unsigned short* xsb  = (unsigned short*)((char*)d_ws + HBUF_BYTES);
    unsigned short* wout = (unsigned short*)((char*)d_ws + HBUF_BYTES + XS_BYTES);

    prep_x0<<<B * D, 64, 0, stream>>>(input, Win, bin, xsb);
    prep_xs<<<(T * B * DP + 255) / 256, 256, 0, stream>>>(target, xsb);
    prep_misc<<<(2 * D * H + 2 * B * H + 255) / 256, 256, 0, stream>>>(fWout, bWout, wout, hbuf);

    void* args[] = { &hbuf, &xsb, &wout,
                     (void*)&fWih, (void*)&fWhh, (void*)&fb,
                     (void*)&bWih, (void*)&bWhh, (void*)&bb,
                     (void*)&fbout, (void*)&bbout, &out };
    hipLaunchCooperativeKernel((void*)lstm_main, dim3(256), dim3(256), args, 0, stream);
}

// Round 2
// 22411.295 us; speedup vs baseline: 1.3958x; 1.3958x over previous
//
#include <hip/hip_runtime.h>
#include <hip/hip_bf16.h>
#include <cstdint>
#include <cstddef>

#define H   1024
#define D   80
#define DP  96          // D padded to multiple of 32 (zero-padded)
#define T   512
#define B   64
#define NG  32          // gate rows per block (4 gates x 8 hidden units)
#define KP  1032        // LDS row stride for Whh slice (+8 bf16 pad)
#define KPI 104         // LDS row stride for Wih slice

typedef __attribute__((ext_vector_type(8))) short bf16x8;   // 8 bf16 (MFMA A/B frag)
typedef __attribute__((ext_vector_type(4))) float f32x4;    // MFMA C/D frag

// ws layout
#define HBUF_ELEMS ((size_t)2 * (T + 1) * B * H)            // bf16 h history, slot 0 = h_{-1}=0
#define HBUF_BYTES (HBUF_ELEMS * 2)
#define XS_ELEMS   ((size_t)T * B * DP)                     // bf16 teacher-forced inputs (padded)
#define XS_BYTES   (XS_ELEMS * 2)
#define WOUT_ELEMS ((size_t)2 * D * H)                      // bf16 W_out both decoders
#define WOUT_BYTES (WOUT_ELEMS * 2)
#define NFLAG      256                                       // one monotonic flag per block
#define FSTRIDE    4                                         // uints (16 B apart)

__device__ __forceinline__ unsigned short f2bf(float x) {
    unsigned int u = __float_as_uint(x);
    unsigned int r = (u + 0x7FFFu + ((u >> 16) & 1u)) >> 16;   // RNE
    return (unsigned short)r;
}

// ---- prep: x0 = input[T-1] @ W_in^T + b_in ----
__global__ void prep_x0(const float* __restrict__ inp, const float* __restrict__ Win,
                        const float* __restrict__ bin, unsigned short* __restrict__ xs)
{
    int o = blockIdx.x;                // 0 .. B*D-1
    int b = o / D, d = o % D;
    int lane = threadIdx.x;
    const float* irow = inp + ((size_t)(T - 1) * B + b) * H;
    const float* wrow = Win + (size_t)d * H;
    float s = 0.f;
    for (int k = lane; k < H; k += 64) s += irow[k] * wrow[k];
    for (int off = 32; off > 0; off >>= 1) s += __shfl_down(s, off, 64);
    if (lane == 0) xs[b * DP + d] = f2bf(s + bin[d]);
}

// ---- prep: xs[t] = target[t-1] (t>=1), zero pads ----
__global__ void prep_xs(const float* __restrict__ tgt, unsigned short* __restrict__ xs)
{
    int idx = blockIdx.x * 256 + threadIdx.x;
    if (idx >= T * B * DP) return;
    int t = idx / (B * DP);
    int r = idx % (B * DP);
    int b = r / DP, d = r % DP;
    if (d >= D) { xs[idx] = 0; return; }
    if (t == 0) return;
    xs[idx] = f2bf(tgt[((size_t)(t - 1) * B + b) * D + d]);
}

// ---- prep: W_out->bf16, zero h slot 0, zero flags ----
__global__ void prep_misc(const float* __restrict__ fWout, const float* __restrict__ bWout,
                          unsigned short* __restrict__ woutbf, unsigned short* __restrict__ hbuf,
                          unsigned int* __restrict__ flags)
{
    int idx = blockIdx.x * 256 + threadIdx.x;
    const int NW = 2 * D * H;
    const int NZ = 2 * B * H;
    const int NF = NFLAG * FSTRIDE;
    if (idx < NW) {
        int dec = idx / (D * H); int rr = idx % (D * H);
        woutbf[idx] = f2bf((dec ? bWout : fWout)[rr]);
    } else if (idx < NW + NZ) {
        int z = idx - NW;
        int dec = z / (B * H); int rr = z % (B * H);
        hbuf[(size_t)dec * (T + 1) * B * H + rr] = 0;
    } else if (idx < NW + NZ + NF) {
        flags[idx - NW - NZ] = 0;
    }
}

// ---- main persistent kernel: 256 blocks x 256 threads (1 block/CU) ----
__global__ void __launch_bounds__(256, 1)
lstm_main(unsigned short* __restrict__ hbuf,
          const unsigned short* __restrict__ xs,
          const unsigned short* __restrict__ woutbf,
          unsigned int* __restrict__ flags,
          const float* __restrict__ fWih, const float* __restrict__ fWhh, const float* __restrict__ fbias,
          const float* __restrict__ bWih, const float* __restrict__ bWhh, const float* __restrict__ bbias,
          const float* __restrict__ fbout, const float* __restrict__ bbout,
          float* __restrict__ out)
{
    const int bid  = blockIdx.x;
    const int dec  = bid >> 7;          // 0 = fwd, 1 = bwd
    const int blk  = bid & 127;
    const int u0   = blk << 3;          // first of 8 owned hidden units
    const int tid  = threadIdx.x;
    const int wave = tid >> 6;
    const int lane = tid & 63;
    const int l15  = lane & 15;
    const int quad = lane >> 4;
    const int koff = quad * 8;

    __shared__ unsigned short sWhh[NG][KP];    // 66 KB
    __shared__ unsigned short sWih[NG][KPI];   // 6.5 KB
    __shared__ float sBias[NG];
    __shared__ float sG[B][33];
    __shared__ float sC[B][8];
    __shared__ bf16x8 sH[B];                   // packed h slice for vector store

    const float* Wih  = dec ? bWih  : fWih;
    const float* Whh  = dec ? bWhh  : fWhh;
    const float* bias = dec ? bbias : fbias;

    for (int e = tid; e < NG * H; e += 256) {
        int n = e >> 10, k = e & (H - 1);
        int row = (n >> 3) * H + u0 + (n & 7);
        sWhh[n][k] = f2bf(Whh[(size_t)row * H + k]);
    }
    for (int e = tid; e < NG * KPI; e += 256) {
        int n = e / KPI, dd = e % KPI;
        int row = (n >> 3) * H + u0 + (n & 7);
        sWih[n][dd] = (dd < D) ? f2bf(Wih[(size_t)row * D + dd]) : 0;
    }
    if (tid < NG) {
        int row = (tid >> 3) * H + u0 + (tid & 7);
        sBias[tid] = bias[row];
    }
    for (int e = tid; e < B * 8; e += 256) sC[e >> 3][e & 7] = 0.f;
    __syncthreads();

    const int m = wave * 16 + l15;   // batch row this lane loads for A-frags
    unsigned int* myflag = flags + (size_t)bid * FSTRIDE;
    const unsigned int* pollflag = flags + ((size_t)(dec * 128) + (tid & 127)) * FSTRIDE;

    for (int t = 0; t < T; ++t) {
        f32x4 acc0 = {0.f, 0.f, 0.f, 0.f};
        f32x4 acc1 = {0.f, 0.f, 0.f, 0.f};

        // x_t @ Wih^T first — independent of h_t, hides in the wait window
        const unsigned short* xrow = xs + ((size_t)t * B + m) * DP;
        #pragma unroll
        for (int kb = 0; kb < DP / 32; ++kb) {
            bf16x8 a  = *(const bf16x8*)(xrow + kb * 32 + koff);
            bf16x8 b0 = *(const bf16x8*)(&sWih[l15][kb * 32 + koff]);
            bf16x8 b1 = *(const bf16x8*)(&sWih[16 + l15][kb * 32 + koff]);
            acc0 = __builtin_amdgcn_mfma_f32_16x16x32_bf16(a, b0, acc0, 0, 0, 0);
            acc1 = __builtin_amdgcn_mfma_f32_16x16x32_bf16(a, b1, acc1, 0, 0, 0);
        }

        // wait for all producers of this decoder to have finished step t-1
        if (t > 0) {
            if (tid < 128) {
                while (__hip_atomic_load(pollflag, __ATOMIC_RELAXED,
                                         __HIP_MEMORY_SCOPE_AGENT) < (unsigned)t) {
                    __builtin_amdgcn_s_sleep(1);
                }
            }
            __syncthreads();
            __threadfence();   // acquire: invalidate stale L1/L2 before reading h_t
        }

        // G[64 x 32] += h_t @ Whh_slice^T   (K = 1024)
        const unsigned short* hrow = hbuf + (((size_t)(dec * (T + 1) + t) * B + m) * H);
        #pragma unroll 16
        for (int kb = 0; kb < H / 32; ++kb) {
            bf16x8 a  = *(const bf16x8*)(hrow + kb * 32 + koff);
            bf16x8 b0 = *(const bf16x8*)(&sWhh[l15][kb * 32 + koff]);
            bf16x8 b1 = *(const bf16x8*)(&sWhh[16 + l15][kb * 32 + koff]);
            acc0 = __builtin_amdgcn_mfma_f32_16x16x32_bf16(a, b0, acc0, 0, 0, 0);
            acc1 = __builtin_amdgcn_mfma_f32_16x16x32_bf16(a, b1, acc1, 0, 0, 0);
        }
        #pragma unroll
        for (int r = 0; r < 4; ++r) {
            sG[wave * 16 + quad * 4 + r][l15]      = acc0[r];
            sG[wave * 16 + quad * 4 + r][16 + l15] = acc1[r];
        }
        __syncthreads();

        // elementwise gate math; pack h slice into LDS
        #pragma unroll
        for (int p = tid; p < B * 8; p += 256) {
            int b = p >> 3, j = p & 7;
            float gi = sG[b][j]      + sBias[j];
            float gf = sG[b][8 + j]  + sBias[8 + j];
            float gg = sG[b][16 + j] + sBias[16 + j];
            float go = sG[b][24 + j] + sBias[24 + j];
            float i_ = 1.f / (1.f + __expf(-gi));
            float f_ = 1.f / (1.f + __expf(-gf));
            float g_ = tanhf(gg);
            float o_ = 1.f / (1.f + __expf(-go));
            float c  = f_ * sC[b][j] + i_ * g_;
            sC[b][j] = c;
            ((unsigned short*)&sH[b])[j] = f2bf(o_ * tanhf(c));
        }
        __syncthreads();

        // one dwordx4 store per lane of wave 0 publishes the whole slice
        if (tid < 64) {
            *(bf16x8*)(hbuf + ((size_t)(dec * (T + 1) + t + 1) * B + tid) * H + u0) = sH[tid];
        }
        __threadfence();   // release: drain + write back before flag
        if (tid == 0) {
            __hip_atomic_store(myflag, (unsigned)(t + 1), __ATOMIC_RELAXED,
                               __HIP_MEMORY_SCOPE_AGENT);
        }
    }

    // wait for BOTH decoders to finish everything (output tiles span both)
    {
        const unsigned int* fp = flags + (size_t)tid * FSTRIDE;
        while (__hip_atomic_load(fp, __ATOMIC_RELAXED, __HIP_MEMORY_SCOPE_AGENT) < (unsigned)T) {
            __builtin_amdgcn_s_sleep(1);
        }
        __syncthreads();
        __threadfence();
    }

    // ---- output projection: Y[dec][t] = h_{t+1-index} @ W_out^T + b_out ----
    for (int qq = 0; qq < 4; ++qq) {
        int q    = bid * 4 + qq;          // 0 .. 1023
        int ydec = q >> 9;
        int yt   = q & 511;
        const float* bout = ydec ? bbout : fbout;
        const unsigned short* hr = hbuf + ((size_t)(ydec * (T + 1) + yt + 1) * B + m) * H;
        const unsigned short* wb = woutbf + (size_t)ydec * D * H;
        #pragma unroll
        for (int nt = 0; nt < 5; ++nt) {
            f32x4 acc = {0.f, 0.f, 0.f, 0.f};
            const unsigned short* wrow = wb + (size_t)(nt * 16 + l15) * H;
            #pragma unroll 8
            for (int kb = 0; kb < H / 32; ++kb) {
                bf16x8 a  = *(const bf16x8*)(hr + kb * 32 + koff);
                bf16x8 bf = *(const bf16x8*)(wrow + kb * 32 + koff);
                acc = __builtin_amdgcn_mfma_f32_16x16x32_bf16(a, bf, acc, 0, 0, 0);
            }
            float bo = bout[nt * 16 + l15];
            #pragma unroll
            for (int r = 0; r < 4; ++r) {
                int bb_ = wave * 16 + quad * 4 + r;
                out[((size_t)(ydec * T + yt) * B + bb_) * D + nt * 16 + l15] = acc[r] + bo;
            }
        }
    }
}

extern "C" void kernel_launch(void* const* d_in, const int* in_sizes, int n_in,
                              void* d_out, int out_size, void* d_ws, size_t ws_size,
                              hipStream_t stream)
{
    const float* input  = (const float*)d_in[0];
    const float* target = (const float*)d_in[1];
    const float* Win    = (const float*)d_in[2];
    const float* bin    = (const float*)d_in[3];
    const float* fWih   = (const float*)d_in[4];
    const float* fWhh   = (const float*)d_in[5];
    const float* fb     = (const float*)d_in[6];
    const float* fWout  = (const float*)d_in[7];
    const float* fbout  = (const float*)d_in[8];
    const float* bWih   = (const float*)d_in[9];
    const float* bWhh   = (const float*)d_in[10];
    const float* bb     = (const float*)d_in[11];
    const float* bWout  = (const float*)d_in[12];
    const float* bbout  = (const float*)d_in[13];
    float* out = (float*)d_out;

    unsigned short* hbuf  = (unsigned short*)d_ws;
    unsigned short* xsb   = (unsigned short*)((char*)d_ws + HBUF_BYTES);
    unsigned short* wout  = (unsigned short*)((char*)d_ws + HBUF_BYTES + XS_BYTES);
    unsigned int*   flags = (unsigned int*)((char*)d_ws + HBUF_BYTES + XS_BYTES + WOUT_BYTES);

    prep_x0<<<B * D, 64, 0, stream>>>(input, Win, bin, xsb);
    prep_xs<<<(T * B * DP + 255) / 256, 256, 0, stream>>>(target, xsb);
    {
        int n = 2 * D * H + 2 * B * H + NFLAG * FSTRIDE;
        prep_misc<<<(n + 255) / 256, 256, 0, stream>>>(fWout, bWout, wout, hbuf, flags);
    }

    void* args[] = { &hbuf, &xsb, &wout, &flags,
                     (void*)&fWih, (void*)&fWhh, (void*)&fb,
                     (void*)&bWih, (void*)&bWhh, (void*)&bb,
                     (void*)&fbout, (void*)&bbout, &out };
    hipLaunchCooperativeKernel((void*)lstm_main, dim3(256), dim3(256), args, 0, stream);
}

// Round 5
// 9226.547 us; speedup vs baseline: 3.3904x; 2.4290x over previous
//
#include <hip/hip_runtime.h>
#include <hip/hip_bf16.h>
#include <cstdint>
#include <cstddef>

#define H   1024
#define D   80
#define DP  96          // D padded to multiple of 32 (zero-padded)
#define T   512
#define B   64
#define NG  32          // gate rows per block (4 gates x 8 hidden units)
#define KP  1032        // LDS row stride for Whh slice (+8 bf16 pad)
#define KPI 104         // LDS row stride for Wih slice

typedef __attribute__((ext_vector_type(8))) short bf16x8;   // 8 bf16 (MFMA A/B frag)
typedef __attribute__((ext_vector_type(4))) float f32x4;    // MFMA C/D frag

// ws layout
#define HBUF_ELEMS ((size_t)2 * (T + 1) * B * H)            // bf16 h history, slot 0 = h_{-1}=0
#define HBUF_BYTES (HBUF_ELEMS * 2)
#define XS_ELEMS   ((size_t)T * B * DP)                     // bf16 teacher-forced inputs (padded)
#define XS_BYTES   (XS_ELEMS * 2)
#define WOUT_ELEMS ((size_t)2 * D * H)                      // bf16 W_out both decoders
#define WOUT_BYTES (WOUT_ELEMS * 2)
#define NFLAG      256                                       // dense: flags[bid], 4B each

__device__ __forceinline__ unsigned short f2bf(float x) {
    unsigned int u = __float_as_uint(x);
    unsigned int r = (u + 0x7FFFu + ((u >> 16) & 1u)) >> 16;   // RNE
    return (unsigned short)r;
}

// device-scope (IC-path) 8-byte load/store: sc0/sc1 bits, bypass L1
__device__ __forceinline__ unsigned long long coh_load8(const unsigned long long* p) {
    return __hip_atomic_load(p, __ATOMIC_RELAXED, __HIP_MEMORY_SCOPE_AGENT);
}
__device__ __forceinline__ void coh_store8(unsigned long long* p, unsigned long long v) {
    __hip_atomic_store(p, v, __ATOMIC_RELAXED, __HIP_MEMORY_SCOPE_AGENT);
}

// ---- prep: x0 = input[T-1] @ W_in^T + b_in ----
__global__ void prep_x0(const float* __restrict__ inp, const float* __restrict__ Win,
                        const float* __restrict__ bin, unsigned short* __restrict__ xs)
{
    int o = blockIdx.x;                // 0 .. B*D-1
    int b = o / D, d = o % D;
    int lane = threadIdx.x;
    const float* irow = inp + ((size_t)(T - 1) * B + b) * H;
    const float* wrow = Win + (size_t)d * H;
    float s = 0.f;
    for (int k = lane; k < H; k += 64) s += irow[k] * wrow[k];
    for (int off = 32; off > 0; off >>= 1) s += __shfl_down(s, off, 64);
    if (lane == 0) xs[b * DP + d] = f2bf(s + bin[d]);
}

// ---- prep: xs[t] = target[t-1] (t>=1), zero pads ----
__global__ void prep_xs(const float* __restrict__ tgt, unsigned short* __restrict__ xs)
{
    int idx = blockIdx.x * 256 + threadIdx.x;
    if (idx >= T * B * DP) return;
    int t = idx / (B * DP);
    int r = idx % (B * DP);
    int b = r / DP, d = r % DP;
    if (d >= D) { xs[idx] = 0; return; }
    if (t == 0) return;
    xs[idx] = f2bf(tgt[((size_t)(t - 1) * B + b) * D + d]);
}

// ---- prep: W_out->bf16, zero h slot 0, zero flags ----
__global__ void prep_misc(const float* __restrict__ fWout, const float* __restrict__ bWout,
                          unsigned short* __restrict__ woutbf, unsigned short* __restrict__ hbuf,
                          unsigned int* __restrict__ flags)
{
    int idx = blockIdx.x * 256 + threadIdx.x;
    const int NW = 2 * D * H;
    const int NZ = 2 * B * H;
    if (idx < NW) {
        int dec = idx / (D * H); int rr = idx % (D * H);
        woutbf[idx] = f2bf((dec ? bWout : fWout)[rr]);
    } else if (idx < NW + NZ) {
        int z = idx - NW;
        int dec = z / (B * H); int rr = z % (B * H);
        hbuf[(size_t)dec * (T + 1) * B * H + rr] = 0;
    } else if (idx < NW + NZ + NFLAG) {
        flags[idx - NW - NZ] = 0;
    }
}

// ---- main persistent kernel: 256 blocks x 256 threads (1 block/CU) ----
__global__ void __launch_bounds__(256, 1)
lstm_main(unsigned short* __restrict__ hbuf,
          const unsigned short* __restrict__ xs,
          const unsigned short* __restrict__ woutbf,
          unsigned int* __restrict__ flags,
          const float* __restrict__ fWih, const float* __restrict__ fWhh, const float* __restrict__ fbias,
          const float* __restrict__ bWih, const float* __restrict__ bWhh, const float* __restrict__ bbias,
          const float* __restrict__ fbout, const float* __restrict__ bbout,
          float* __restrict__ out)
{
    const int bid  = blockIdx.x;
    const int dec  = bid >> 7;          // 0 = fwd, 1 = bwd
    const int blk  = bid & 127;
    const int u0   = blk << 3;          // first of 8 owned hidden units
    const int tid  = threadIdx.x;
    const int wave = tid >> 6;
    const int lane = tid & 63;
    const int l15  = lane & 15;
    const int quad = lane >> 4;
    const int koff = quad * 8;

    __shared__ unsigned short sWhh[NG][KP];    // 66 KB
    __shared__ unsigned short sWih[NG][KPI];   // 6.5 KB
    __shared__ float sBias[NG];
    __shared__ float sG[B][33];
    __shared__ float sC[B][8];
    __shared__ bf16x8 sH[B];                   // packed h slice for vector publish

    const float* Wih  = dec ? bWih  : fWih;
    const float* Whh  = dec ? bWhh  : fWhh;
    const float* bias = dec ? bbias : fbias;

    for (int e = tid; e < NG * H; e += 256) {
        int n = e >> 10, k = e & (H - 1);
        int row = (n >> 3) * H + u0 + (n & 7);
        sWhh[n][k] = f2bf(Whh[(size_t)row * H + k]);
    }
    for (int e = tid; e < NG * KPI; e += 256) {
        int n = e / KPI, dd = e % KPI;
        int row = (n >> 3) * H + u0 + (n & 7);
        sWih[n][dd] = (dd < D) ? f2bf(Wih[(size_t)row * D + dd]) : 0;
    }
    if (tid < NG) {
        int row = (tid >> 3) * H + u0 + (tid & 7);
        sBias[tid] = bias[row];
    }
    for (int e = tid; e < B * 8; e += 256) sC[e >> 3][e & 7] = 0.f;
    __syncthreads();

    const int m = wave * 16 + l15;   // batch row this lane loads for A-frags
    unsigned int* myflag = flags + bid;
    const unsigned int* pf = flags + dec * 128;   // this decoder's 128 producer flags

    // u64 view of hbuf (4 bf16 per u64); one h row (H=1024 bf16) = 256 u64 -> << 8
    const unsigned long long* hq = (const unsigned long long*)hbuf;

    for (int t = 0; t < T; ++t) {
        f32x4 acc0 = {0.f, 0.f, 0.f, 0.f};
        f32x4 acc1 = {0.f, 0.f, 0.f, 0.f};

        // x_t @ Wih^T first — independent of h_t, hides in the wait window
        const unsigned short* xrow = xs + ((size_t)t * B + m) * DP;
        #pragma unroll
        for (int kb = 0; kb < DP / 32; ++kb) {
            bf16x8 a  = *(const bf16x8*)(xrow + kb * 32 + koff);
            bf16x8 b0 = *(const bf16x8*)(&sWih[l15][kb * 32 + koff]);
            bf16x8 b1 = *(const bf16x8*)(&sWih[16 + l15][kb * 32 + koff]);
            acc0 = __builtin_amdgcn_mfma_f32_16x16x32_bf16(a, b0, acc0, 0, 0, 0);
            acc1 = __builtin_amdgcn_mfma_f32_16x16x32_bf16(a, b1, acc1, 0, 0, 0);
        }

        // wave 0 polls all 128 producer flags (2/lane, dense), then ONE acquire fence
        if (t > 0) {
            if (wave == 0) {
                const unsigned tgt = (unsigned)t;
                for (;;) {
                    unsigned f0 = __hip_atomic_load(&pf[lane],      __ATOMIC_RELAXED,
                                                    __HIP_MEMORY_SCOPE_AGENT);
                    unsigned f1 = __hip_atomic_load(&pf[64 + lane], __ATOMIC_RELAXED,
                                                    __HIP_MEMORY_SCOPE_AGENT);
                    if (__all((f0 >= tgt) && (f1 >= tgt))) break;
                    __builtin_amdgcn_s_sleep(1);
                }
                __builtin_amdgcn_fence(__ATOMIC_ACQUIRE, "agent");   // one buffer_inv / block
            }
            __syncthreads();
        }

        // G[64 x 32] += h_t @ Whh_slice^T (K = 1024), h read on the IC path
        {
            const unsigned long long* hrow =
                hq + (((size_t)(dec * (T + 1) + t) * B + m) << 8) + (quad << 1);
            #pragma unroll 16
            for (int kb = 0; kb < H / 32; ++kb) {
                union { unsigned long long q[2]; bf16x8 v; } A;
                A.q[0] = coh_load8(hrow + kb * 8);
                A.q[1] = coh_load8(hrow + kb * 8 + 1);
                bf16x8 b0 = *(const bf16x8*)(&sWhh[l15][kb * 32 + koff]);
                bf16x8 b1 = *(const bf16x8*)(&sWhh[16 + l15][kb * 32 + koff]);
                acc0 = __builtin_amdgcn_mfma_f32_16x16x32_bf16(A.v, b0, acc0, 0, 0, 0);
                acc1 = __builtin_amdgcn_mfma_f32_16x16x32_bf16(A.v, b1, acc1, 0, 0, 0);
            }
        }
        #pragma unroll
        for (int r = 0; r < 4; ++r) {
            sG[wave * 16 + quad * 4 + r][l15]      = acc0[r];
            sG[wave * 16 + quad * 4 + r][16 + l15] = acc1[r];
        }
        __syncthreads();

        // elementwise gate math; pack h slice into LDS
        #pragma unroll
        for (int p = tid; p < B * 8; p += 256) {
            int b = p >> 3, j = p & 7;
            float gi = sG[b][j]      + sBias[j];
            float gf = sG[b][8 + j]  + sBias[8 + j];
            float gg = sG[b][16 + j] + sBias[16 + j];
            float go = sG[b][24 + j] + sBias[24 + j];
            float i_ = 1.f / (1.f + __expf(-gi));
            float f_ = 1.f / (1.f + __expf(-gf));
            float g_ = tanhf(gg);
            float o_ = 1.f / (1.f + __expf(-go));
            float c  = f_ * sC[b][j] + i_ * g_;
            sC[b][j] = c;
            ((unsigned short*)&sH[b])[j] = f2bf(o_ * tanhf(c));
        }
        __syncthreads();

        // wave 0 publishes the slice on the IC path; lane 0 release-stores the flag
        // (release emits the required drain/writeback ordering ONCE per block per step)
        if (tid < 64) {
            const unsigned long long* src = (const unsigned long long*)&sH[tid];
            unsigned long long v0 = src[0], v1 = src[1];
            unsigned long long* dst = (unsigned long long*)
                (hbuf + ((size_t)(dec * (T + 1) + t + 1) * B + tid) * H + u0);
            coh_store8(dst, v0);
            coh_store8(dst + 1, v1);
        }
        if (tid == 0) {
            __hip_atomic_store(myflag, (unsigned)(t + 1), __ATOMIC_RELEASE,
                               __HIP_MEMORY_SCOPE_AGENT);
        }
    }

    // wait for BOTH decoders to finish everything (output tiles span both)
    {
        if (wave == 0) {
            for (;;) {
                unsigned f0 = __hip_atomic_load(&flags[lane],       __ATOMIC_RELAXED, __HIP_MEMORY_SCOPE_AGENT);
                unsigned f1 = __hip_atomic_load(&flags[64 + lane],  __ATOMIC_RELAXED, __HIP_MEMORY_SCOPE_AGENT);
                unsigned f2 = __hip_atomic_load(&flags[128 + lane], __ATOMIC_RELAXED, __HIP_MEMORY_SCOPE_AGENT);
                unsigned f3 = __hip_atomic_load(&flags[192 + lane], __ATOMIC_RELAXED, __HIP_MEMORY_SCOPE_AGENT);
                if (__all((f0 >= (unsigned)T) && (f1 >= (unsigned)T) &&
                          (f2 >= (unsigned)T) && (f3 >= (unsigned)T))) break;
                __builtin_amdgcn_s_sleep(1);
            }
            __builtin_amdgcn_fence(__ATOMIC_ACQUIRE, "agent");
        }
        __syncthreads();
    }

    // ---- output projection: Y[dec][t] = h @ W_out^T + b_out ----
    for (int qq = 0; qq < 4; ++qq) {
        int q    = bid * 4 + qq;          // 0 .. 1023
        int ydec = q >> 9;
        int yt   = q & 511;
        const float* bout = ydec ? bbout : fbout;
        const unsigned short* hr = hbuf + ((size_t)(ydec * (T + 1) + yt + 1) * B + m) * H;
        const unsigned short* wb = woutbf + (size_t)ydec * D * H;
        #pragma unroll
        for (int nt = 0; nt < 5; ++nt) {
            f32x4 acc = {0.f, 0.f, 0.f, 0.f};
            const unsigned short* wrow = wb + (size_t)(nt * 16 + l15) * H;
            #pragma unroll 8
            for (int kb = 0; kb < H / 32; ++kb) {
                bf16x8 a  = *(const bf16x8*)(hr + kb * 32 + koff);
                bf16x8 bf = *(const bf16x8*)(wrow + kb * 32 + koff);
                acc = __builtin_amdgcn_mfma_f32_16x16x32_bf16(a, bf, acc, 0, 0, 0);
            }
            float bo = bout[nt * 16 + l15];
            #pragma unroll
            for (int r = 0; r < 4; ++r) {
                int bb_ = wave * 16 + quad * 4 + r;
                out[((size_t)(ydec * T + yt) * B + bb_) * D + nt * 16 + l15] = acc[r] + bo;
            }
        }
    }
}

extern "C" void kernel_launch(void* const* d_in, const int* in_sizes, int n_in,
                              void* d_out, int out_size, void* d_ws, size_t ws_size,
                              hipStream_t stream)
{
    const float* input  = (const float*)d_in[0];
    const float* target = (const float*)d_in[1];
    const float* Win    = (const float*)d_in[2];
    const float* bin    = (const float*)d_in[3];
    const float* fWih   = (const float*)d_in[4];
    const float* fWhh   = (const float*)d_in[5];
    const float* fb     = (const float*)d_in[6];
    const float* fWout  = (const float*)d_in[7];
    const float* fbout  = (const float*)d_in[8];
    const float* bWih   = (const float*)d_in[9];
    const float* bWhh   = (const float*)d_in[10];
    const float* bb     = (const float*)d_in[11];
    const float* bWout  = (const float*)d_in[12];
    const float* bbout  = (const float*)d_in[13];
    float* out = (float*)d_out;

    unsigned short* hbuf  = (unsigned short*)d_ws;
    unsigned short* xsb   = (unsigned short*)((char*)d_ws + HBUF_BYTES);
    unsigned short* wout  = (unsigned short*)((char*)d_ws + HBUF_BYTES + XS_BYTES);
    unsigned int*   flags = (unsigned int*)((char*)d_ws + HBUF_BYTES + XS_BYTES + WOUT_BYTES);

    prep_x0<<<B * D, 64, 0, stream>>>(input, Win, bin, xsb);
    prep_xs<<<(T * B * DP + 255) / 256, 256, 0, stream>>>(target, xsb);
    {
        int n = 2 * D * H + 2 * B * H + NFLAG;
        prep_misc<<<(n + 255) / 256, 256, 0, stream>>>(fWout, bWout, wout, hbuf, flags);
    }

    void* args[] = { &hbuf, &xsb, &wout, &flags,
                     (void*)&fWih, (void*)&fWhh, (void*)&fb,
                     (void*)&bWih, (void*)&bWhh, (void*)&bb,
                     (void*)&fbout, (void*)&bbout, &out };
    hipLaunchCooperativeKernel((void*)lstm_main, dim3(256), dim3(256), args, 0, stream);
}